// Round 27
// baseline (330.647 us; speedup 1.0000x reference)
//
#include <hip/hip_runtime.h>
#include <hip/hip_bf16.h>
#include <math.h>

#define NTOK 768
#define CS   384
#define CZ   128
#define NH   12
#define INF_ 100000.0f
#define EPS_ 1e-8f

typedef unsigned int  uint32;
typedef __attribute__((ext_vector_type(8))) short bf16x8;
typedef __attribute__((ext_vector_type(4))) float f32x4;

__device__ __forceinline__ float bflo(uint32 u) { return __uint_as_float((u & 0xffffu) << 16); }
__device__ __forceinline__ float bfhi(uint32 u) { return __uint_as_float(u & 0xffff0000u); }
// scalar-cast pack: compiler emits v_cvt_pk_bf16_f32
__device__ __forceinline__ uint32 pkbf(float a, float b) {
    union { unsigned short s[2]; uint32 u; } r;
    __hip_bfloat16 ha = __float2bfloat16(a);
    __hip_bfloat16 hb = __float2bfloat16(b);
    __builtin_memcpy(&r.s[0], &ha, 2);
    __builtin_memcpy(&r.s[1], &hb, 2);
    return r.u;
}

#define QK_SCALE 0.14433756729740643f   // sqrt(1/48)
#define B_SCALE  0.5773502691896258f    // sqrt(1/3)
#define HW_SCALE 0.13608276348795434f   // sqrt(1/54)

// ---------------------------------------------------------------------------
// K1a: tiled GEMM. RAW[col][tok] = sum_k s[tok][k] * Wcat[k][col]  (no bias).
// ---------------------------------------------------------------------------
__global__ __launch_bounds__(256) void k1a_gemm(
    const float* __restrict__ s,
    const float* __restrict__ wq, const float* __restrict__ wkv,
    const float* __restrict__ wqp, const float* __restrict__ wkvp,
    float* __restrict__ RAW)
{
    __shared__ float sA[32][72];   // [k][m]
    __shared__ float sB[32][72];   // [k][n]
    const int tid  = threadIdx.x;
    const int tok0 = blockIdx.x * 64;
    const int col0 = blockIdx.y * 64;

    const int m0 = (tid & 15) * 4;
    const int n0 = (tid >> 4) * 4;

    float4 acc[4];
    #pragma unroll
    for (int nn = 0; nn < 4; nn++) acc[nn] = make_float4(0.f, 0.f, 0.f, 0.f);

    const int lam = tid >> 2, lak = (tid & 3) * 8;
    const int lbk = tid >> 3, lbc = (tid & 7) * 8;
    const int gcol = col0 + lbc;
    const float* wsrc; int wwidth, woff;
    if (gcol < 192)      { wsrc = wq;   wwidth = 192; woff = gcol; }
    else if (gcol < 576) { wsrc = wkv;  wwidth = 384; woff = gcol - 192; }
    else if (gcol < 720) { wsrc = wqp;  wwidth = 144; woff = gcol - 576; }
    else                 { wsrc = wkvp; wwidth = 432; woff = gcol - 720; }

    for (int kb = 0; kb < CS; kb += 32) {
        const float4 a0 = *(const float4*)&s[(tok0 + lam) * CS + kb + lak];
        const float4 a1 = *(const float4*)&s[(tok0 + lam) * CS + kb + lak + 4];
        const float4 b0 = *(const float4*)&wsrc[(size_t)(kb + lbk) * wwidth + woff];
        const float4 b1 = *(const float4*)&wsrc[(size_t)(kb + lbk) * wwidth + woff + 4];
        __syncthreads();
        sA[lak + 0][lam] = a0.x; sA[lak + 1][lam] = a0.y;
        sA[lak + 2][lam] = a0.z; sA[lak + 3][lam] = a0.w;
        sA[lak + 4][lam] = a1.x; sA[lak + 5][lam] = a1.y;
        sA[lak + 6][lam] = a1.z; sA[lak + 7][lam] = a1.w;
        *(float4*)&sB[lbk][lbc]     = b0;
        *(float4*)&sB[lbk][lbc + 4] = b1;
        __syncthreads();
        #pragma unroll
        for (int k = 0; k < 32; k++) {
            const float4 av = *(const float4*)&sA[k][m0];
            const float4 bv = *(const float4*)&sB[k][n0];
            acc[0].x += av.x * bv.x; acc[0].y += av.y * bv.x; acc[0].z += av.z * bv.x; acc[0].w += av.w * bv.x;
            acc[1].x += av.x * bv.y; acc[1].y += av.y * bv.y; acc[1].z += av.z * bv.y; acc[1].w += av.w * bv.y;
            acc[2].x += av.x * bv.z; acc[2].y += av.y * bv.z; acc[2].z += av.z * bv.z; acc[2].w += av.w * bv.z;
            acc[3].x += av.x * bv.w; acc[3].y += av.y * bv.w; acc[3].z += av.z * bv.w; acc[3].w += av.w * bv.w;
        }
    }
    #pragma unroll
    for (int nn = 0; nn < 4; nn++)
        *(float4*)&RAW[(size_t)(col0 + n0 + nn) * NTOK + tok0 + m0] = acc[nn];
}

// ---------------------------------------------------------------------------
// K1b: bias + rigid transform + GEMM-operand packing for the logit GEMM.
// ---------------------------------------------------------------------------
__global__ __launch_bounds__(256) void k1b_finish(
    const float* __restrict__ RAW,
    const float* __restrict__ rot, const float* __restrict__ trans,
    const float* __restrict__ bq, const float* __restrict__ bkv,
    const float* __restrict__ bqp, const float* __restrict__ bkvp,
    const float* __restrict__ head_weights,
    float* __restrict__ VT, float* __restrict__ QP, float* __restrict__ VPT,
    float* __restrict__ AP, float* __restrict__ BP,
    float* __restrict__ RQN, float* __restrict__ CKN)
{
    __shared__ float hwS[NH];
    const int tid = threadIdx.x;
    const int t  = blockIdx.x * 16 + (tid & 15);
    const int wk = tid >> 4;                      // 16 walkers

    if (tid < NH) hwS[tid] = logf(1.0f + expf(head_weights[tid])) * HW_SCALE;

    float R[9], T3[3];
    #pragma unroll
    for (int x = 0; x < 9; x++) R[x] = rot[t * 9 + x];
    #pragma unroll
    for (int x = 0; x < 3; x++) T3[x] = trans[t * 3 + x];
    __syncthreads();

    // q -> AP (scaled)
    for (int col = wk; col < 192; col += 16) {
        const int h = col >> 4, c = col & 15;
        AP[(size_t)(h * 28 + c) * NTOK + t] = QK_SCALE * (RAW[(size_t)col * NTOK + t] + bq[col]);
    }
    // k -> BP, v -> VT
    for (int idx = wk; idx < 192; idx += 16) {
        const int h = idx >> 4, c = idx & 15;
        BP[(size_t)(h * 28 + c) * NTOK + t] = RAW[(size_t)(192 + h * 32 + c) * NTOK + t] + bkv[h * 32 + c];
        VT[idx * NTOK + t] = RAW[(size_t)(192 + h * 32 + 16 + c) * NTOK + t] + bkv[h * 32 + 16 + c];
    }
    // q points: pidx = h*4+p -> QP + AP (hw-scaled)
    for (int pidx = wk; pidx < 48; pidx += 16) {
        const int h = pidx >> 2, p = pidx & 3;
        const float r0 = RAW[(size_t)(576 + 0 * 48 + pidx) * NTOK + t] + bqp[0 * 48 + pidx];
        const float r1 = RAW[(size_t)(576 + 1 * 48 + pidx) * NTOK + t] + bqp[1 * 48 + pidx];
        const float r2 = RAW[(size_t)(576 + 2 * 48 + pidx) * NTOK + t] + bqp[2 * 48 + pidx];
        #pragma unroll
        for (int x = 0; x < 3; x++) {
            const float v = R[x*3+0]*r0 + R[x*3+1]*r1 + R[x*3+2]*r2 + T3[x];
            QP[t * 144 + pidx * 3 + x] = v;
            AP[(size_t)(h * 28 + 16 + p * 3 + x) * NTOK + t] = hwS[h] * v;
        }
    }
    // kv points: pidx = h*12+pp; pp<4 -> BP (kp), else -> VPT
    for (int pidx = wk; pidx < 144; pidx += 16) {
        const int h = pidx / 12, pp = pidx % 12;
        const float r0 = RAW[(size_t)(720 + 0 * 144 + pidx) * NTOK + t] + bkvp[0 * 144 + pidx];
        const float r1 = RAW[(size_t)(720 + 1 * 144 + pidx) * NTOK + t] + bkvp[1 * 144 + pidx];
        const float r2 = RAW[(size_t)(720 + 2 * 144 + pidx) * NTOK + t] + bkvp[2 * 144 + pidx];
        #pragma unroll
        for (int x = 0; x < 3; x++) {
            const float v = R[x*3+0]*r0 + R[x*3+1]*r1 + R[x*3+2]*r2 + T3[x];
            if (pp < 4) BP[(size_t)(h * 28 + 16 + pp * 3 + x) * NTOK + t] = v;
            else        VPT[((h * 8 + pp - 4) * 3 + x) * NTOK + t] = v;
        }
    }
    __syncthreads();
    // norms (per head, per token)
    if (wk < NH) {
        const int h = wk;
        float sq = 0.f, sk = 0.f;
        #pragma unroll
        for (int d = 0; d < 12; d++) {
            const float a = QP[t * 144 + h * 12 + d];
            sq += a * a;
            const float b = BP[(size_t)(h * 28 + 16 + d) * NTOK + t];
            sk += b * b;
        }
        RQN[h * NTOK + t] = -0.5f * hwS[h] * sq;
        CKN[h * NTOK + t] = -0.5f * hwS[h] * sk;
    }
}

// ---------------------------------------------------------------------------
// K23 (fused z-projection + attention): one block per row i, 768 thr = 12 wv.
// R26: LDS 99.8KB -> 1 blk/CU = latency-bound (VALUBusy 24%, HBM 0.79 TB/s).
// Now: bias stored bf16 (bbH 18.5KB, was 37KB f32) and wBs (13KB) OVERLAYS
// the pzL region (dead after fragment build; extra barrier added) ->
// LDS ~68.1KB -> 2 blocks/CU, 24 waves, phases of adjacent blocks overlap.
// C/D layout m89-verified: col = lane&15 (=o), row = (lane>>4)*4+reg (=j).
// ---------------------------------------------------------------------------
__global__ __launch_bounds__(768) void k23_fused(
    const float* __restrict__ z, const float* __restrict__ wb, const float* __restrict__ bb,
    const float* __restrict__ wdz, const float* __restrict__ bdz,
    const float* __restrict__ AP, const float* __restrict__ BP,
    const float* __restrict__ RQN, const float* __restrict__ CKN,
    const float* __restrict__ mask,
    const float* __restrict__ VT, const float* __restrict__ VPT,
    float* __restrict__ O, float* __restrict__ OPT, float* __restrict__ OPAIR)
{
    // layout: [0, 49408) pzL uint32[32][386]  (overlaid by wBs ushort[48*136] early)
    //         [49408, 67936) bbH uint32[12][386]
    __shared__ __align__(16) uint32 sm32[(49408 + 18528) / 4];
    uint32* pzL = sm32;                                  // [c][x] stride 386
    unsigned short* wBs = (unsigned short*)sm32;         // [o][k] stride 136 (early only)
    uint32* bbH = sm32 + 49408 / 4;                      // [o][x] stride 386
    __shared__ float bbS[12], bdzS[32];

    const int i = blockIdx.x, tid = threadIdx.x;
    const int h = tid >> 6;          // wave id: phase A j-tile owner; phase B head
    const int l = tid & 63;

    // stage weights as bf16, k-contiguous rows (into the overlay region)
    for (int idx = tid; idx < 48 * 64; idx += 768) {
        const int o = idx >> 6, k2 = (idx & 63) * 2;
        float f0, f1;
        if (o < 12)      { f0 = wb[k2 * 12 + o];         f1 = wb[(k2 + 1) * 12 + o]; }
        else if (o < 44) { f0 = wdz[k2 * 32 + (o - 12)]; f1 = wdz[(k2 + 1) * 32 + (o - 12)]; }
        else             { f0 = 0.f; f1 = 0.f; }
        *(uint32*)&wBs[o * 136 + k2] = pkbf(f0, f1);
    }
    if (tid < 12) bbS[tid] = bb[tid];
    else if (tid >= 32 && tid < 64) bdzS[tid - 32] = bdz[tid - 32];
    __syncthreads();

    // B fragments: lane: col = l&15, k = ks*32 + (l>>4)*8
    bf16x8 Bf[3][4];
    #pragma unroll
    for (int t = 0; t < 3; t++)
        #pragma unroll
        for (int ks = 0; ks < 4; ks++)
            Bf[t][ks] = *(const bf16x8*)&wBs[(t * 16 + (l & 15)) * 136 + ks * 32 + (l >> 4) * 8];
    __syncthreads();   // wBs dead; pzL may now overwrite the overlay region

    // ---- Phase A: 4 sub-tiles of 16 j, this wave's j-range starts at h*64
    const float* zb = z + ((size_t)i * NTOK + h * 64 + (l & 15)) * CZ + (l >> 4) * 8;
    float4 pa[8];
    #pragma unroll
    for (int ks = 0; ks < 4; ks++) {
        pa[2 * ks]     = *(const float4*)&zb[ks * 32];
        pa[2 * ks + 1] = *(const float4*)&zb[ks * 32 + 4];
    }

    #pragma unroll
    for (int st = 0; st < 4; st++) {
        const int jb = h * 64 + st * 16;
        union { uint32 u[4]; bf16x8 v; } Au[4];
        #pragma unroll
        for (int ks = 0; ks < 4; ks++) {
            Au[ks].u[0] = pkbf(pa[2 * ks].x,     pa[2 * ks].y);
            Au[ks].u[1] = pkbf(pa[2 * ks].z,     pa[2 * ks].w);
            Au[ks].u[2] = pkbf(pa[2 * ks + 1].x, pa[2 * ks + 1].y);
            Au[ks].u[3] = pkbf(pa[2 * ks + 1].z, pa[2 * ks + 1].w);
        }
        if (st < 3) {
            const float* zn = zb + (size_t)(st + 1) * 16 * CZ;
            #pragma unroll
            for (int ks = 0; ks < 4; ks++) {
                pa[2 * ks]     = *(const float4*)&zn[ks * 32];
                pa[2 * ks + 1] = *(const float4*)&zn[ks * 32 + 4];
            }
        }

        f32x4 acc[3];
        #pragma unroll
        for (int t = 0; t < 3; t++) acc[t] = (f32x4){0.f, 0.f, 0.f, 0.f};
        #pragma unroll
        for (int ks = 0; ks < 4; ks++)
            #pragma unroll
            for (int t = 0; t < 3; t++)
                acc[t] = __builtin_amdgcn_mfma_f32_16x16x32_bf16(Au[ks].v, Bf[t][ks], acc[t], 0, 0, 0);

        // scatter: lane l, reg v -> j = jb + (l>>4)*4 + v, o = t*16 + (l&15)
        const int jq = jb + (l >> 4) * 4;
        #pragma unroll
        for (int t = 0; t < 3; t++) {
            const int o = t * 16 + (l & 15);
            if (o < 12) {
                const float bz = bbS[o];
                bbH[o * 386 + (jq >> 1)]     = pkbf(acc[t][0] + bz, acc[t][1] + bz);
                bbH[o * 386 + (jq >> 1) + 1] = pkbf(acc[t][2] + bz, acc[t][3] + bz);
            } else if (o < 44) {
                const int c = o - 12;
                const float bz = bdzS[c];
                pzL[c * 386 + (jq >> 1)]     = pkbf(acc[t][0] + bz, acc[t][1] + bz);
                pzL[c * 386 + (jq >> 1) + 1] = pkbf(acc[t][2] + bz, acc[t][3] + bz);
            }
        }
    }
    __syncthreads();

    // ---- Phase B: wave h = head h; logits in registers from LDS bias + BP
    float ap[28];
    #pragma unroll
    for (int k = 0; k < 28; k++) ap[k] = AP[(size_t)(h * 28 + k) * NTOK + i];
    const float rq = RQN[h * NTOK + i];
    const float mi = mask[i];

    f32x4 lg[3];
    #pragma unroll
    for (int qb = 0; qb < 3; qb++) {
        const int j4 = qb * 256 + l * 4;
        const float4 ck  = *(const float4*)&CKN[h * NTOK + j4];
        const uint32 bx = bbH[h * 386 + (j4 >> 1)];
        const uint32 by = bbH[h * 386 + (j4 >> 1) + 1];
        const float4 mj  = *(const float4*)&mask[j4];
        f32x4 a;
        a[0] = B_SCALE * bflo(bx) + rq + ck.x + INF_ * (mi * mj.x - 1.0f);
        a[1] = B_SCALE * bfhi(bx) + rq + ck.y + INF_ * (mi * mj.y - 1.0f);
        a[2] = B_SCALE * bflo(by) + rq + ck.z + INF_ * (mi * mj.z - 1.0f);
        a[3] = B_SCALE * bfhi(by) + rq + ck.w + INF_ * (mi * mj.w - 1.0f);
        #pragma unroll
        for (int k = 0; k < 28; k++) {
            const float4 bp = *(const float4*)&BP[(size_t)(h * 28 + k) * NTOK + j4];
            a[0] += ap[k] * bp.x; a[1] += ap[k] * bp.y;
            a[2] += ap[k] * bp.z; a[3] += ap[k] * bp.w;
        }
        lg[qb] = a;
    }

    // softmax over 12 register values x 64 lanes
    float m = -3.0e38f;
    #pragma unroll
    for (int qb = 0; qb < 3; qb++)
        #pragma unroll
        for (int v = 0; v < 4; v++) m = fmaxf(m, lg[qb][v]);
    #pragma unroll
    for (int off = 32; off >= 1; off >>= 1) m = fmaxf(m, __shfl_xor(m, off));
    float ssum = 0.0f;
    #pragma unroll
    for (int qb = 0; qb < 3; qb++)
        #pragma unroll
        for (int v = 0; v < 4; v++) {
            const float e = __expf(lg[qb][v] - m);
            lg[qb][v] = e;
            ssum += e;
        }
    #pragma unroll
    for (int off = 32; off >= 1; off >>= 1) ssum += __shfl_xor(ssum, off);
    const float inv = 1.0f / ssum;
    #pragma unroll
    for (int qb = 0; qb < 3; qb++)
        #pragma unroll
        for (int v = 0; v < 4; v++) lg[qb][v] *= inv;

    // wave-cooperative weighted sums (VT/VPT global, coalesced)
    #pragma unroll 2
    for (int r = 0; r < 40; r++) {
        const float4* src = (r < 16) ? (const float4*)&VT[(h * 16 + r) * NTOK]
                                     : (const float4*)&VPT[(h * 24 + (r - 16)) * NTOK];
        const float4 v0 = src[l], v1 = src[64 + l], v2 = src[128 + l];
        float acc = lg[0][0]*v0.x + lg[0][1]*v0.y + lg[0][2]*v0.z + lg[0][3]*v0.w
                  + lg[1][0]*v1.x + lg[1][1]*v1.y + lg[1][2]*v1.z + lg[1][3]*v1.w
                  + lg[2][0]*v2.x + lg[2][1]*v2.y + lg[2][2]*v2.z + lg[2][3]*v2.w;
        #pragma unroll
        for (int off = 32; off >= 1; off >>= 1) acc += __shfl_xor(acc, off);
        if (l == 0) {
            if (r < 16) O[i * 192 + h * 16 + r] = acc;
            else        OPT[i * 288 + h * 24 + (r - 16)] = acc;
        }
    }
    // o_pair: 32 bf16 rows from LDS (pairs of adjacent j per u32)
    #pragma unroll 2
    for (int c = 0; c < 32; c++) {
        float a = 0.f;
        #pragma unroll
        for (int it = 0; it < 3; it++) {
            const uint32* p2 = &pzL[c * 386 + it * 128 + 2 * l];
            const uint32 ux = p2[0], uy = p2[1];
            a += lg[it][0] * bflo(ux) + lg[it][1] * bfhi(ux)
               + lg[it][2] * bflo(uy) + lg[it][3] * bfhi(uy);
        }
        #pragma unroll
        for (int off = 32; off >= 1; off >>= 1) a += __shfl_xor(a, off);
        if (l == 0) OPAIR[i * 384 + h * 32 + c] = a;
    }
}

// ---------------------------------------------------------------------------
// K4: inverse rotation + norms + concat + final linear (8 tokens/block).
// GEMM loop reads f via ds_read_b128 (4 k's per LDS instr).
// ---------------------------------------------------------------------------
#define K4T 8
__global__ __launch_bounds__(256) void k4_out(
    const float* __restrict__ O, const float* __restrict__ OPT, const float* __restrict__ OPAIR,
    const float* __restrict__ rot, const float* __restrict__ trans,
    const float* __restrict__ wout, const float* __restrict__ bout,
    float* __restrict__ out)
{
    __shared__ float f[K4T][960];
    const int n0 = blockIdx.x * K4T, tid = threadIdx.x;

    for (int idx = tid; idx < K4T * 192; idx += 256) {
        const int t = idx / 192, k = idx % 192;
        f[t][k] = O[(n0 + t) * 192 + k];
    }
    for (int idx = tid; idx < K4T * 384; idx += 256) {
        const int t = idx / 384, k = idx % 384;
        f[t][576 + k] = OPAIR[(n0 + t) * 384 + k];
    }
    for (int idx = tid; idx < K4T * 96; idx += 256) {
        const int t = idx / 96, hp = idx % 96;
        const int n = n0 + t;
        const float vx = OPT[n * 288 + hp * 3 + 0] - trans[n * 3 + 0];
        const float vy = OPT[n * 288 + hp * 3 + 1] - trans[n * 3 + 1];
        const float vz = OPT[n * 288 + hp * 3 + 2] - trans[n * 3 + 2];
        const float o0 = rot[n*9+0]*vx + rot[n*9+3]*vy + rot[n*9+6]*vz;
        const float o1 = rot[n*9+1]*vx + rot[n*9+4]*vy + rot[n*9+7]*vz;
        const float o2 = rot[n*9+2]*vx + rot[n*9+5]*vy + rot[n*9+8]*vz;
        f[t][192 + hp] = o0;
        f[t][288 + hp] = o1;
        f[t][384 + hp] = o2;
        f[t][480 + hp] = sqrtf(o0*o0 + o1*o1 + o2*o2 + EPS_);
    }
    __syncthreads();

    for (int o = tid; o < 384; o += 256) {
        float acc[K4T];
        #pragma unroll
        for (int t = 0; t < K4T; t++) acc[t] = bout[o];
        for (int kq = 0; kq < 240; kq++) {
            float4 fv[K4T];
            #pragma unroll
            for (int t = 0; t < K4T; t++) fv[t] = *(const float4*)&f[t][kq * 4];
            #pragma unroll
            for (int kk = 0; kk < 4; kk++) {
                const float wv = wout[(kq * 4 + kk) * 384 + o];
                #pragma unroll
                for (int t = 0; t < K4T; t++) {
                    const float fe = (kk == 0) ? fv[t].x : (kk == 1) ? fv[t].y
                                   : (kk == 2) ? fv[t].z : fv[t].w;
                    acc[t] += fe * wv;
                }
            }
        }
        #pragma unroll
        for (int t = 0; t < K4T; t++) out[(n0 + t) * 384 + o] = acc[t];
    }
}

// ---------------------------------------------------------------------------
extern "C" void kernel_launch(void* const* d_in, const int* in_sizes, int n_in,
                              void* d_out, int out_size, void* d_ws, size_t ws_size,
                              hipStream_t stream) {
    (void)in_sizes; (void)n_in; (void)out_size; (void)ws_size;
    const float* s     = (const float*)d_in[0];
    const float* z     = (const float*)d_in[1];
    const float* rot   = (const float*)d_in[2];
    const float* trans = (const float*)d_in[3];
    const float* mask  = (const float*)d_in[4];
    const float* wq    = (const float*)d_in[5];
    const float* bq    = (const float*)d_in[6];
    const float* wkv   = (const float*)d_in[7];
    const float* bkv   = (const float*)d_in[8];
    const float* wqp   = (const float*)d_in[9];
    const float* bqp   = (const float*)d_in[10];
    const float* wkvp  = (const float*)d_in[11];
    const float* bkvp  = (const float*)d_in[12];
    const float* wb    = (const float*)d_in[13];
    const float* bb    = (const float*)d_in[14];
    const float* wdz   = (const float*)d_in[15];
    const float* bdz   = (const float*)d_in[16];
    const float* hwts  = (const float*)d_in[17];
    const float* wout  = (const float*)d_in[18];
    const float* bout  = (const float*)d_in[19];
    float* out = (float*)d_out;

    float* ws = (float*)d_ws;
    float* Q     = ws;                       // 147456 (unused, kept for layout)
    float* KT    = Q     + 147456;           // 147456 (unused)
    float* VT    = KT    + 147456;           // 147456
    float* QP    = VT    + 147456;           // 110592
    float* KPT   = QP    + 110592;           // 110592 (unused)
    float* VPT   = KPT   + 110592;           // 221184
    float* O     = VPT   + 221184;           // 147456
    float* OPT   = O     + 147456;           // 221184
    float* OPAIR = OPT   + 221184;           // 294912
    float* RAW   = OPAIR + 294912;           // 884736 (k1a scratch)
    float* AP    = RAW   + 884736;           // 258048
    float* BP    = AP  + 258048;             // 258048
    float* RQN   = BP  + 258048;             // 9216
    float* CKN   = RQN + 9216;               // 9216

    hipLaunchKernelGGL(k1a_gemm, dim3(NTOK / 64, 1152 / 64), dim3(256), 0, stream,
                       s, wq, wkv, wqp, wkvp, RAW);
    hipLaunchKernelGGL(k1b_finish, dim3(NTOK / 16), dim3(256), 0, stream,
                       RAW, rot, trans, bq, bkv, bqp, bkvp, hwts,
                       VT, QP, VPT, AP, BP, RQN, CKN);
    hipLaunchKernelGGL(k23_fused, dim3(NTOK), dim3(768), 0, stream,
                       z, wb, bb, wdz, bdz,
                       AP, BP, RQN, CKN, mask, VT, VPT,
                       O, OPT, OPAIR);
    hipLaunchKernelGGL(k4_out, dim3(NTOK / K4T), dim3(256), 0, stream,
                       O, OPT, OPAIR, rot, trans, wout, bout, out);
}

// Round 28
// 322.897 us; speedup vs baseline: 1.0240x; 1.0240x over previous
//
#include <hip/hip_runtime.h>
#include <hip/hip_bf16.h>
#include <math.h>

#define NTOK 768
#define CS   384
#define CZ   128
#define NH   12
#define INF_ 100000.0f
#define EPS_ 1e-8f

typedef unsigned int  uint32;
typedef unsigned short ushort;
typedef __attribute__((ext_vector_type(8))) short bf16x8;
typedef __attribute__((ext_vector_type(4))) float f32x4;

__device__ __forceinline__ float bflo(uint32 u) { return __uint_as_float((u & 0xffffu) << 16); }
__device__ __forceinline__ float bfhi(uint32 u) { return __uint_as_float(u & 0xffff0000u); }
// scalar-cast pack: compiler emits v_cvt_pk_bf16_f32
__device__ __forceinline__ uint32 pkbf(float a, float b) {
    union { ushort s[2]; uint32 u; } r;
    __hip_bfloat16 ha = __float2bfloat16(a);
    __hip_bfloat16 hb = __float2bfloat16(b);
    __builtin_memcpy(&r.s[0], &ha, 2);
    __builtin_memcpy(&r.s[1], &hb, 2);
    return r.u;
}
__device__ __forceinline__ ushort bf16h(float x) {
    __hip_bfloat16 h = __float2bfloat16(x);
    ushort r; __builtin_memcpy(&r, &h, 2); return r;
}
__device__ __forceinline__ float bfdec(ushort u) { return __uint_as_float(((uint32)u) << 16); }

#define QK_SCALE 0.14433756729740643f   // sqrt(1/48)
#define B_SCALE  0.5773502691896258f    // sqrt(1/3)
#define HW_SCALE 0.13608276348795434f   // sqrt(1/54)

// ---------------------------------------------------------------------------
// K1a: tiled GEMM. RAW[col][tok] = sum_k s[tok][k] * Wcat[k][col]  (no bias).
// ---------------------------------------------------------------------------
__global__ __launch_bounds__(256) void k1a_gemm(
    const float* __restrict__ s,
    const float* __restrict__ wq, const float* __restrict__ wkv,
    const float* __restrict__ wqp, const float* __restrict__ wkvp,
    float* __restrict__ RAW)
{
    __shared__ float sA[32][72];   // [k][m]
    __shared__ float sB[32][72];   // [k][n]
    const int tid  = threadIdx.x;
    const int tok0 = blockIdx.x * 64;
    const int col0 = blockIdx.y * 64;

    const int m0 = (tid & 15) * 4;
    const int n0 = (tid >> 4) * 4;

    float4 acc[4];
    #pragma unroll
    for (int nn = 0; nn < 4; nn++) acc[nn] = make_float4(0.f, 0.f, 0.f, 0.f);

    const int lam = tid >> 2, lak = (tid & 3) * 8;
    const int lbk = tid >> 3, lbc = (tid & 7) * 8;
    const int gcol = col0 + lbc;
    const float* wsrc; int wwidth, woff;
    if (gcol < 192)      { wsrc = wq;   wwidth = 192; woff = gcol; }
    else if (gcol < 576) { wsrc = wkv;  wwidth = 384; woff = gcol - 192; }
    else if (gcol < 720) { wsrc = wqp;  wwidth = 144; woff = gcol - 576; }
    else                 { wsrc = wkvp; wwidth = 432; woff = gcol - 720; }

    for (int kb = 0; kb < CS; kb += 32) {
        const float4 a0 = *(const float4*)&s[(tok0 + lam) * CS + kb + lak];
        const float4 a1 = *(const float4*)&s[(tok0 + lam) * CS + kb + lak + 4];
        const float4 b0 = *(const float4*)&wsrc[(size_t)(kb + lbk) * wwidth + woff];
        const float4 b1 = *(const float4*)&wsrc[(size_t)(kb + lbk) * wwidth + woff + 4];
        __syncthreads();
        sA[lak + 0][lam] = a0.x; sA[lak + 1][lam] = a0.y;
        sA[lak + 2][lam] = a0.z; sA[lak + 3][lam] = a0.w;
        sA[lak + 4][lam] = a1.x; sA[lak + 5][lam] = a1.y;
        sA[lak + 6][lam] = a1.z; sA[lak + 7][lam] = a1.w;
        *(float4*)&sB[lbk][lbc]     = b0;
        *(float4*)&sB[lbk][lbc + 4] = b1;
        __syncthreads();
        #pragma unroll
        for (int k = 0; k < 32; k++) {
            const float4 av = *(const float4*)&sA[k][m0];
            const float4 bv = *(const float4*)&sB[k][n0];
            acc[0].x += av.x * bv.x; acc[0].y += av.y * bv.x; acc[0].z += av.z * bv.x; acc[0].w += av.w * bv.x;
            acc[1].x += av.x * bv.y; acc[1].y += av.y * bv.y; acc[1].z += av.z * bv.y; acc[1].w += av.w * bv.y;
            acc[2].x += av.x * bv.z; acc[2].y += av.y * bv.z; acc[2].z += av.z * bv.z; acc[2].w += av.w * bv.z;
            acc[3].x += av.x * bv.w; acc[3].y += av.y * bv.w; acc[3].z += av.z * bv.w; acc[3].w += av.w * bv.w;
        }
    }
    #pragma unroll
    for (int nn = 0; nn < 4; nn++)
        *(float4*)&RAW[(size_t)(col0 + n0 + nn) * NTOK + tok0 + m0] = acc[nn];
}

// ---------------------------------------------------------------------------
// K1b: bias + rigid transform + operand packing. Shared phase-B operands
// (BPH, VTH, VPTH) stored bf16 (R27: f32 re-reads at L3 latency were the
// wall — 2GB across blocks; bf16 halves bytes and load count).
// ---------------------------------------------------------------------------
__global__ __launch_bounds__(256) void k1b_finish(
    const float* __restrict__ RAW,
    const float* __restrict__ rot, const float* __restrict__ trans,
    const float* __restrict__ bq, const float* __restrict__ bkv,
    const float* __restrict__ bqp, const float* __restrict__ bkvp,
    const float* __restrict__ head_weights,
    ushort* __restrict__ VTH, float* __restrict__ QP, ushort* __restrict__ VPTH,
    float* __restrict__ AP, ushort* __restrict__ BPH,
    float* __restrict__ RQN, float* __restrict__ CKN)
{
    __shared__ float hwS[NH];
    const int tid = threadIdx.x;
    const int t  = blockIdx.x * 16 + (tid & 15);
    const int wk = tid >> 4;                      // 16 walkers

    if (tid < NH) hwS[tid] = logf(1.0f + expf(head_weights[tid])) * HW_SCALE;

    float R[9], T3[3];
    #pragma unroll
    for (int x = 0; x < 9; x++) R[x] = rot[t * 9 + x];
    #pragma unroll
    for (int x = 0; x < 3; x++) T3[x] = trans[t * 3 + x];
    __syncthreads();

    // q -> AP (scaled, f32: consumed as wave-uniform scalars)
    for (int col = wk; col < 192; col += 16) {
        const int h = col >> 4, c = col & 15;
        AP[(size_t)(h * 28 + c) * NTOK + t] = QK_SCALE * (RAW[(size_t)col * NTOK + t] + bq[col]);
    }
    // k -> BPH (bf16), v -> VTH (bf16)
    for (int idx = wk; idx < 192; idx += 16) {
        const int h = idx >> 4, c = idx & 15;
        BPH[(size_t)(h * 28 + c) * NTOK + t] = bf16h(RAW[(size_t)(192 + h * 32 + c) * NTOK + t] + bkv[h * 32 + c]);
        VTH[(size_t)idx * NTOK + t] = bf16h(RAW[(size_t)(192 + h * 32 + 16 + c) * NTOK + t] + bkv[h * 32 + 16 + c]);
    }
    // q points: pidx = h*4+p -> QP (f32) + AP (hw-scaled f32)
    for (int pidx = wk; pidx < 48; pidx += 16) {
        const int h = pidx >> 2, p = pidx & 3;
        const float r0 = RAW[(size_t)(576 + 0 * 48 + pidx) * NTOK + t] + bqp[0 * 48 + pidx];
        const float r1 = RAW[(size_t)(576 + 1 * 48 + pidx) * NTOK + t] + bqp[1 * 48 + pidx];
        const float r2 = RAW[(size_t)(576 + 2 * 48 + pidx) * NTOK + t] + bqp[2 * 48 + pidx];
        #pragma unroll
        for (int x = 0; x < 3; x++) {
            const float v = R[x*3+0]*r0 + R[x*3+1]*r1 + R[x*3+2]*r2 + T3[x];
            QP[t * 144 + pidx * 3 + x] = v;
            AP[(size_t)(h * 28 + 16 + p * 3 + x) * NTOK + t] = hwS[h] * v;
        }
    }
    // kv points: pidx = h*12+pp; pp<4 -> BPH (kp, bf16), else -> VPTH (bf16)
    for (int pidx = wk; pidx < 144; pidx += 16) {
        const int h = pidx / 12, pp = pidx % 12;
        const float r0 = RAW[(size_t)(720 + 0 * 144 + pidx) * NTOK + t] + bkvp[0 * 144 + pidx];
        const float r1 = RAW[(size_t)(720 + 1 * 144 + pidx) * NTOK + t] + bkvp[1 * 144 + pidx];
        const float r2 = RAW[(size_t)(720 + 2 * 144 + pidx) * NTOK + t] + bkvp[2 * 144 + pidx];
        #pragma unroll
        for (int x = 0; x < 3; x++) {
            const float v = R[x*3+0]*r0 + R[x*3+1]*r1 + R[x*3+2]*r2 + T3[x];
            if (pp < 4) BPH[(size_t)(h * 28 + 16 + pp * 3 + x) * NTOK + t] = bf16h(v);
            else        VPTH[(size_t)((h * 8 + pp - 4) * 3 + x) * NTOK + t] = bf16h(v);
        }
    }
    __syncthreads();
    // norms (per head, per token); kp decoded from bf16 (matches logit math)
    if (wk < NH) {
        const int h = wk;
        float sq = 0.f, sk = 0.f;
        #pragma unroll
        for (int d = 0; d < 12; d++) {
            const float a = QP[t * 144 + h * 12 + d];
            sq += a * a;
            const float b = bfdec(BPH[(size_t)(h * 28 + 16 + d) * NTOK + t]);
            sk += b * b;
        }
        RQN[h * NTOK + t] = -0.5f * hwS[h] * sq;
        CKN[h * NTOK + t] = -0.5f * hwS[h] * sk;
    }
}

// ---------------------------------------------------------------------------
// K23 (fused z-projection + attention): one block per row i, 768 thr = 12 wv.
// Phase A: MFMA z-GEMM -> LDS (bbH/pzL bf16). Phase B: register logits
// (bf16 BPH), softmax, wave-cooperative sums (bf16 VTH/VPTH).
// LDS ~68.6KB; wBs overlays pzL (dead after fragment build).
// C/D layout m89-verified: col = lane&15 (=o), row = (lane>>4)*4+reg (=j).
// ---------------------------------------------------------------------------
__global__ __launch_bounds__(768) void k23_fused(
    const float* __restrict__ z, const float* __restrict__ wb, const float* __restrict__ bb,
    const float* __restrict__ wdz, const float* __restrict__ bdz,
    const float* __restrict__ AP, const ushort* __restrict__ BPH,
    const float* __restrict__ RQN, const float* __restrict__ CKN,
    const float* __restrict__ mask,
    const ushort* __restrict__ VTH, const ushort* __restrict__ VPTH,
    float* __restrict__ O, float* __restrict__ OPT, float* __restrict__ OPAIR)
{
    // layout: [0, 49408) pzL uint32[32][386]  (overlaid by wBs ushort[48*136] early)
    //         [49408, 67936) bbH uint32[12][386]
    __shared__ __align__(16) uint32 sm32[(49408 + 18528) / 4];
    uint32* pzL = sm32;                                  // [c][x] stride 386
    ushort* wBs = (ushort*)sm32;                         // [o][k] stride 136 (early only)
    uint32* bbH = sm32 + 49408 / 4;                      // [o][x] stride 386
    __shared__ float bbS[12], bdzS[32];

    const int i = blockIdx.x, tid = threadIdx.x;
    const int h = tid >> 6;          // wave id: phase A j-tile owner; phase B head
    const int l = tid & 63;

    // stage weights as bf16, k-contiguous rows (into the overlay region)
    for (int idx = tid; idx < 48 * 64; idx += 768) {
        const int o = idx >> 6, k2 = (idx & 63) * 2;
        float f0, f1;
        if (o < 12)      { f0 = wb[k2 * 12 + o];         f1 = wb[(k2 + 1) * 12 + o]; }
        else if (o < 44) { f0 = wdz[k2 * 32 + (o - 12)]; f1 = wdz[(k2 + 1) * 32 + (o - 12)]; }
        else             { f0 = 0.f; f1 = 0.f; }
        *(uint32*)&wBs[o * 136 + k2] = pkbf(f0, f1);
    }
    if (tid < 12) bbS[tid] = bb[tid];
    else if (tid >= 32 && tid < 64) bdzS[tid - 32] = bdz[tid - 32];
    __syncthreads();

    // B fragments: lane: col = l&15, k = ks*32 + (l>>4)*8
    bf16x8 Bf[3][4];
    #pragma unroll
    for (int t = 0; t < 3; t++)
        #pragma unroll
        for (int ks = 0; ks < 4; ks++)
            Bf[t][ks] = *(const bf16x8*)&wBs[(t * 16 + (l & 15)) * 136 + ks * 32 + (l >> 4) * 8];
    __syncthreads();   // wBs dead; pzL may now overwrite the overlay region

    // ---- Phase A: 4 sub-tiles of 16 j, this wave's j-range starts at h*64
    const float* zb = z + ((size_t)i * NTOK + h * 64 + (l & 15)) * CZ + (l >> 4) * 8;
    float4 pa[8];
    #pragma unroll
    for (int ks = 0; ks < 4; ks++) {
        pa[2 * ks]     = *(const float4*)&zb[ks * 32];
        pa[2 * ks + 1] = *(const float4*)&zb[ks * 32 + 4];
    }

    #pragma unroll
    for (int st = 0; st < 4; st++) {
        const int jb = h * 64 + st * 16;
        union { uint32 u[4]; bf16x8 v; } Au[4];
        #pragma unroll
        for (int ks = 0; ks < 4; ks++) {
            Au[ks].u[0] = pkbf(pa[2 * ks].x,     pa[2 * ks].y);
            Au[ks].u[1] = pkbf(pa[2 * ks].z,     pa[2 * ks].w);
            Au[ks].u[2] = pkbf(pa[2 * ks + 1].x, pa[2 * ks + 1].y);
            Au[ks].u[3] = pkbf(pa[2 * ks + 1].z, pa[2 * ks + 1].w);
        }
        if (st < 3) {
            const float* zn = zb + (size_t)(st + 1) * 16 * CZ;
            #pragma unroll
            for (int ks = 0; ks < 4; ks++) {
                pa[2 * ks]     = *(const float4*)&zn[ks * 32];
                pa[2 * ks + 1] = *(const float4*)&zn[ks * 32 + 4];
            }
        }

        f32x4 acc[3];
        #pragma unroll
        for (int t = 0; t < 3; t++) acc[t] = (f32x4){0.f, 0.f, 0.f, 0.f};
        #pragma unroll
        for (int ks = 0; ks < 4; ks++)
            #pragma unroll
            for (int t = 0; t < 3; t++)
                acc[t] = __builtin_amdgcn_mfma_f32_16x16x32_bf16(Au[ks].v, Bf[t][ks], acc[t], 0, 0, 0);

        // scatter: lane l, reg v -> j = jb + (l>>4)*4 + v, o = t*16 + (l&15)
        const int jq = jb + (l >> 4) * 4;
        #pragma unroll
        for (int t = 0; t < 3; t++) {
            const int o = t * 16 + (l & 15);
            if (o < 12) {
                const float bz = bbS[o];
                bbH[o * 386 + (jq >> 1)]     = pkbf(acc[t][0] + bz, acc[t][1] + bz);
                bbH[o * 386 + (jq >> 1) + 1] = pkbf(acc[t][2] + bz, acc[t][3] + bz);
            } else if (o < 44) {
                const int c = o - 12;
                const float bz = bdzS[c];
                pzL[c * 386 + (jq >> 1)]     = pkbf(acc[t][0] + bz, acc[t][1] + bz);
                pzL[c * 386 + (jq >> 1) + 1] = pkbf(acc[t][2] + bz, acc[t][3] + bz);
            }
        }
    }
    __syncthreads();

    // ---- Phase B: wave h = head h; logits in registers from LDS bias + BPH
    float ap[28];
    #pragma unroll
    for (int k = 0; k < 28; k++) ap[k] = AP[(size_t)(h * 28 + k) * NTOK + i];
    const float rq = RQN[h * NTOK + i];
    const float mi = mask[i];

    f32x4 lg[3];
    #pragma unroll
    for (int qb = 0; qb < 3; qb++) {
        const int j4 = qb * 256 + l * 4;
        const float4 ck  = *(const float4*)&CKN[h * NTOK + j4];
        const uint32 bx = bbH[h * 386 + (j4 >> 1)];
        const uint32 by = bbH[h * 386 + (j4 >> 1) + 1];
        const float4 mj  = *(const float4*)&mask[j4];
        f32x4 a;
        a[0] = B_SCALE * bflo(bx) + rq + ck.x + INF_ * (mi * mj.x - 1.0f);
        a[1] = B_SCALE * bfhi(bx) + rq + ck.y + INF_ * (mi * mj.y - 1.0f);
        a[2] = B_SCALE * bflo(by) + rq + ck.z + INF_ * (mi * mj.z - 1.0f);
        a[3] = B_SCALE * bfhi(by) + rq + ck.w + INF_ * (mi * mj.w - 1.0f);
        #pragma unroll
        for (int k = 0; k < 28; k++) {
            const uint2 u = *(const uint2*)&BPH[(size_t)(h * 28 + k) * NTOK + j4];
            a[0] += ap[k] * bflo(u.x); a[1] += ap[k] * bfhi(u.x);
            a[2] += ap[k] * bflo(u.y); a[3] += ap[k] * bfhi(u.y);
        }
        lg[qb] = a;
    }

    // softmax over 12 register values x 64 lanes
    float m = -3.0e38f;
    #pragma unroll
    for (int qb = 0; qb < 3; qb++)
        #pragma unroll
        for (int v = 0; v < 4; v++) m = fmaxf(m, lg[qb][v]);
    #pragma unroll
    for (int off = 32; off >= 1; off >>= 1) m = fmaxf(m, __shfl_xor(m, off));
    float ssum = 0.0f;
    #pragma unroll
    for (int qb = 0; qb < 3; qb++)
        #pragma unroll
        for (int v = 0; v < 4; v++) {
            const float e = __expf(lg[qb][v] - m);
            lg[qb][v] = e;
            ssum += e;
        }
    #pragma unroll
    for (int off = 32; off >= 1; off >>= 1) ssum += __shfl_xor(ssum, off);
    const float inv = 1.0f / ssum;
    #pragma unroll
    for (int qb = 0; qb < 3; qb++)
        #pragma unroll
        for (int v = 0; v < 4; v++) lg[qb][v] *= inv;

    // wave-cooperative weighted sums (bf16 rows, uint2 loads, coalesced)
    #pragma unroll 2
    for (int r = 0; r < 40; r++) {
        const ushort* srcH = (r < 16) ? &VTH[(size_t)(h * 16 + r) * NTOK]
                                      : &VPTH[(size_t)(h * 24 + (r - 16)) * NTOK];
        const uint2* s2 = (const uint2*)srcH;
        const uint2 u0 = s2[l], u1 = s2[64 + l], u2 = s2[128 + l];
        float acc = lg[0][0]*bflo(u0.x) + lg[0][1]*bfhi(u0.x) + lg[0][2]*bflo(u0.y) + lg[0][3]*bfhi(u0.y)
                  + lg[1][0]*bflo(u1.x) + lg[1][1]*bfhi(u1.x) + lg[1][2]*bflo(u1.y) + lg[1][3]*bfhi(u1.y)
                  + lg[2][0]*bflo(u2.x) + lg[2][1]*bfhi(u2.x) + lg[2][2]*bflo(u2.y) + lg[2][3]*bfhi(u2.y);
        #pragma unroll
        for (int off = 32; off >= 1; off >>= 1) acc += __shfl_xor(acc, off);
        if (l == 0) {
            if (r < 16) O[i * 192 + h * 16 + r] = acc;
            else        OPT[i * 288 + h * 24 + (r - 16)] = acc;
        }
    }
    // o_pair: 32 bf16 rows from LDS (pairs of adjacent j per u32)
    #pragma unroll 2
    for (int c = 0; c < 32; c++) {
        float a = 0.f;
        #pragma unroll
        for (int it = 0; it < 3; it++) {
            const uint32* p2 = &pzL[c * 386 + it * 128 + 2 * l];
            const uint32 ux = p2[0], uy = p2[1];
            a += lg[it][0] * bflo(ux) + lg[it][1] * bfhi(ux)
               + lg[it][2] * bflo(uy) + lg[it][3] * bfhi(uy);
        }
        #pragma unroll
        for (int off = 32; off >= 1; off >>= 1) a += __shfl_xor(a, off);
        if (l == 0) OPAIR[i * 384 + h * 32 + c] = a;
    }
}

// ---------------------------------------------------------------------------
// K4: inverse rotation + norms + concat + final linear (8 tokens/block).
// ---------------------------------------------------------------------------
#define K4T 8
__global__ __launch_bounds__(256) void k4_out(
    const float* __restrict__ O, const float* __restrict__ OPT, const float* __restrict__ OPAIR,
    const float* __restrict__ rot, const float* __restrict__ trans,
    const float* __restrict__ wout, const float* __restrict__ bout,
    float* __restrict__ out)
{
    __shared__ float f[K4T][960];
    const int n0 = blockIdx.x * K4T, tid = threadIdx.x;

    for (int idx = tid; idx < K4T * 192; idx += 256) {
        const int t = idx / 192, k = idx % 192;
        f[t][k] = O[(n0 + t) * 192 + k];
    }
    for (int idx = tid; idx < K4T * 384; idx += 256) {
        const int t = idx / 384, k = idx % 384;
        f[t][576 + k] = OPAIR[(n0 + t) * 384 + k];
    }
    for (int idx = tid; idx < K4T * 96; idx += 256) {
        const int t = idx / 96, hp = idx % 96;
        const int n = n0 + t;
        const float vx = OPT[n * 288 + hp * 3 + 0] - trans[n * 3 + 0];
        const float vy = OPT[n * 288 + hp * 3 + 1] - trans[n * 3 + 1];
        const float vz = OPT[n * 288 + hp * 3 + 2] - trans[n * 3 + 2];
        const float o0 = rot[n*9+0]*vx + rot[n*9+3]*vy + rot[n*9+6]*vz;
        const float o1 = rot[n*9+1]*vx + rot[n*9+4]*vy + rot[n*9+7]*vz;
        const float o2 = rot[n*9+2]*vx + rot[n*9+5]*vy + rot[n*9+8]*vz;
        f[t][192 + hp] = o0;
        f[t][288 + hp] = o1;
        f[t][384 + hp] = o2;
        f[t][480 + hp] = sqrtf(o0*o0 + o1*o1 + o2*o2 + EPS_);
    }
    __syncthreads();

    for (int o = tid; o < 384; o += 256) {
        float acc[K4T];
        #pragma unroll
        for (int t = 0; t < K4T; t++) acc[t] = bout[o];
        for (int kq = 0; kq < 240; kq++) {
            float4 fv[K4T];
            #pragma unroll
            for (int t = 0; t < K4T; t++) fv[t] = *(const float4*)&f[t][kq * 4];
            #pragma unroll
            for (int kk = 0; kk < 4; kk++) {
                const float wv = wout[(kq * 4 + kk) * 384 + o];
                #pragma unroll
                for (int t = 0; t < K4T; t++) {
                    const float fe = (kk == 0) ? fv[t].x : (kk == 1) ? fv[t].y
                                   : (kk == 2) ? fv[t].z : fv[t].w;
                    acc[t] += fe * wv;
                }
            }
        }
        #pragma unroll
        for (int t = 0; t < K4T; t++) out[(n0 + t) * 384 + o] = acc[t];
    }
}

// ---------------------------------------------------------------------------
extern "C" void kernel_launch(void* const* d_in, const int* in_sizes, int n_in,
                              void* d_out, int out_size, void* d_ws, size_t ws_size,
                              hipStream_t stream) {
    (void)in_sizes; (void)n_in; (void)out_size; (void)ws_size;
    const float* s     = (const float*)d_in[0];
    const float* z     = (const float*)d_in[1];
    const float* rot   = (const float*)d_in[2];
    const float* trans = (const float*)d_in[3];
    const float* mask  = (const float*)d_in[4];
    const float* wq    = (const float*)d_in[5];
    const float* bq    = (const float*)d_in[6];
    const float* wkv   = (const float*)d_in[7];
    const float* bkv   = (const float*)d_in[8];
    const float* wqp   = (const float*)d_in[9];
    const float* bqp   = (const float*)d_in[10];
    const float* wkvp  = (const float*)d_in[11];
    const float* bkvp  = (const float*)d_in[12];
    const float* wb    = (const float*)d_in[13];
    const float* bb    = (const float*)d_in[14];
    const float* wdz   = (const float*)d_in[15];
    const float* bdz   = (const float*)d_in[16];
    const float* hwts  = (const float*)d_in[17];
    const float* wout  = (const float*)d_in[18];
    const float* bout  = (const float*)d_in[19];
    float* out = (float*)d_out;

    float* ws = (float*)d_ws;
    ushort* VTH  = (ushort*)ws;                 // 147456 ushort = 73728 float-slots
    ushort* VPTH = (ushort*)(ws + 73728);       // 221184 ushort = 110592 float-slots
    float* QP    = ws + 73728 + 110592;         // 110592
    float* O     = QP  + 110592;                // 147456
    float* OPT   = O   + 147456;                // 221184
    float* OPAIR = OPT + 221184;                // 294912
    float* RAW   = OPAIR + 294912;              // 884736 (k1a scratch)
    float* AP    = RAW + 884736;                // 258048
    ushort* BPH  = (ushort*)(AP + 258048);      // 258048 ushort = 129024 float-slots
    float* RQN   = AP + 258048 + 129024;        // 9216
    float* CKN   = RQN + 9216;                  // 9216

    hipLaunchKernelGGL(k1a_gemm, dim3(NTOK / 64, 1152 / 64), dim3(256), 0, stream,
                       s, wq, wkv, wqp, wkvp, RAW);
    hipLaunchKernelGGL(k1b_finish, dim3(NTOK / 16), dim3(256), 0, stream,
                       RAW, rot, trans, bq, bkv, bqp, bkvp, hwts,
                       VTH, QP, VPTH, AP, BPH, RQN, CKN);
    hipLaunchKernelGGL(k23_fused, dim3(NTOK), dim3(768), 0, stream,
                       z, wb, bb, wdz, bdz,
                       AP, BPH, RQN, CKN, mask, VTH, VPTH,
                       O, OPT, OPAIR);
    hipLaunchKernelGGL(k4_out, dim3(NTOK / K4T), dim3(256), 0, stream,
                       O, OPT, OPAIR, rot, trans, wout, bout, out);
}